// Round 7
// baseline (550.913 us; speedup 1.0000x reference)
//
#include <hip/hip_runtime.h>

typedef _Float16 f16;
typedef f16  f16x8 __attribute__((ext_vector_type(8)));
typedef f16  f16x4 __attribute__((ext_vector_type(4)));
typedef float f32x4 __attribute__((ext_vector_type(4)));
typedef unsigned int u32;
typedef unsigned long long u64;

// ---- d_ws layout (f16 elems): hi/lo split weights, 352,256 B ----
#define W1T_HI 0        // [4][128][32]  W1T[e][u][f]
#define W1T_LO 16384
#define V1T_HI 32768    // [128][32]
#define V1T_LO 36864
#define W2T_HI 40960    // [4][64][160]  W2T[e][u][k], k = [h1(128), node(32)]
#define W2T_LO 81920
#define V2T_HI 122880   // [64][32]
#define V2T_LO 124928
#define WIT_HI 126976   // [128][96]     WiT[ua][k], k = [h2(64), node(32)]
#define WIT_LO 139264
#define WJT_HI 151552
#define WJT_LO 163840
#define WS_SRC 88064

// ---- dynamic LDS (bytes): 81,920 B = 80 KB -> 2 blocks/CU ----
// ADJ hi/lo unchanged. ANN_HI (16 KB) triple-duty: PT/QT_HI for ALL 8
// waves (w*2048, live only between ann-liveness windows) / f32 merge
// scratch (16 KB; merge1 runs in two u-halves) / ann hi. ANN_LO: ann lo
// plane / PT_LO (w*1024). PTB (8 KB): PERSISTENT node hi+lo planes —
// node fragments are re-read from LDS (volatile, CSE-proof) instead of
// 32 persistent VGPRs.
#define ADJB_HI 0        // f16 [4][64][64], XOR swizzle (unit8 ^ (m&7))      32768 B
#define ADJB_LO 32768    // u8  [4][64][64], same swizzle, straight bytes    16384 B
#define ANNB_HI 49152    // f16 [64][128] ann hi / PT_HI x8 / scr 16KB       16384 B
#define ANNB_LO 65536    // u8  [64][128] ann lo / PT_LO x8                    8192 B
#define PTB     73728    // f16 nodeH[64][32] + nodeLo[64][32], persistent     8192 B
#define LDS_BYTES 81920

__device__ __forceinline__ f32x4 mfma16(f16x8 a, f16x8 b, f32x4 c){
  return __builtin_amdgcn_mfma_f32_16x16x32_f16(a, b, c, 0, 0, 0);
}
// rcp-based activations: exact at +-inf (rcp(inf)=0), no clamp needed, ~6 VALU ops.
__device__ __forceinline__ float fast_tanh(float x){
  float e = __expf(2.f * x);
  return 1.f - 2.f * __builtin_amdgcn_rcpf(e + 1.f);
}
__device__ __forceinline__ float fast_sigmoid(float x){
  return __builtin_amdgcn_rcpf(1.f + __expf(-x));
}

// ---- 8-bit lo-plane codec: byte = top 8 bits of f16(lo), RTN via +0x80.
// Decode = byte into HIGH byte of f16 lane -> 4x v_perm_b32 per 8 elems.
__device__ __forceinline__ unsigned char enc1(float lo){
  f16 h = (f16)lo;
  unsigned short u = __builtin_bit_cast(unsigned short, h);
  return (unsigned char)(((u32)u + 0x80u) >> 8);
}
__device__ __forceinline__ void enc8(unsigned char* p, const float* lo){
  u32 a = 0, b = 0;
  #pragma unroll
  for (int j = 0; j < 4; ++j) a |= (u32)enc1(lo[j]) << (8*j);
  #pragma unroll
  for (int j = 0; j < 4; ++j) b |= (u32)enc1(lo[4+j]) << (8*j);
  uint2 v = {a, b};
  *(uint2*)p = v;
}
__device__ __forceinline__ u32 enc4(const float* lo){
  return (u32)enc1(lo[0]) | ((u32)enc1(lo[1]) << 8)
       | ((u32)enc1(lo[2]) << 16) | ((u32)enc1(lo[3]) << 24);
}
__device__ __forceinline__ f16x8 dec8_w(u32 dx, u32 dy){
  u32 w[4];
  w[0] = __builtin_amdgcn_perm(0u, dx, 0x010c000cu);  // [0]=0,[1]=b0,[2]=0,[3]=b1
  w[1] = __builtin_amdgcn_perm(0u, dx, 0x030c020cu);  // b2, b3
  w[2] = __builtin_amdgcn_perm(0u, dy, 0x010c000cu);  // b4, b5
  w[3] = __builtin_amdgcn_perm(0u, dy, 0x030c020cu);  // b6, b7
  f16x8 r; __builtin_memcpy(&r, w, 16);
  return r;
}
__device__ __forceinline__ f16x8 dec8(const unsigned char* p){
  uint2 d = *(const uint2*)p;
  return dec8_w(d.x, d.y);
}
// volatile variants: CSE/remat-proof (register-diet loads)
__device__ __forceinline__ f16x8 dec8v(const unsigned char* p){
  u64 v = *(const volatile u64*)p;
  return dec8_w((u32)v, (u32)(v >> 32));
}
__device__ __forceinline__ f16x8 lds16v(const f16* p){
  u64 a = ((const volatile u64*)p)[0];
  u64 b = ((const volatile u64*)p)[1];
  u64 w[2] = {a, b};
  f16x8 r; __builtin_memcpy(&r, w, 16);
  return r;
}

__global__ void prep_weights(const float* __restrict__ W1, const float* __restrict__ V1,
                             const float* __restrict__ W2, const float* __restrict__ V2,
                             const float* __restrict__ Wi, const float* __restrict__ Wj,
                             f16* __restrict__ ws){
  int i = blockIdx.x * 256 + threadIdx.x;
  if (i >= WS_SRC) return;
  float v; int hi_off, lo_off, idx;
  int j = i;
  if (j < 16384){ int e = j >> 12, u = (j >> 5) & 127, f = j & 31;
    v = W1[(e*32 + f)*128 + u]; hi_off = W1T_HI; lo_off = W1T_LO; idx = j; }
  else if ((j -= 16384) < 4096){ int u = j >> 5, f = j & 31;
    v = V1[f*128 + u]; hi_off = V1T_HI; lo_off = V1T_LO; idx = j; }
  else if ((j -= 4096) < 40960){ int e = j / 10240, r = j % 10240, u = r / 160, k = r % 160;
    v = W2[e*10240 + k*64 + u]; hi_off = W2T_HI; lo_off = W2T_LO; idx = j; }
  else if ((j -= 40960) < 2048){ int u = j >> 5, f = j & 31;
    v = V2[f*64 + u]; hi_off = V2T_HI; lo_off = V2T_LO; idx = j; }
  else if ((j -= 2048) < 12288){ int ua = j / 96, k = j % 96;
    v = Wi[k*128 + ua]; hi_off = WIT_HI; lo_off = WIT_LO; idx = j; }
  else { j -= 12288; int ua = j / 96, k = j % 96;
    v = Wj[k*128 + ua]; hi_off = WJT_HI; lo_off = WJT_LO; idx = j; }
  f16 h = (f16)v;
  ws[hi_off + idx] = h;
  ws[lo_off + idx] = (f16)(v - (float)h);
}

// one block = one batch; 8 waves; edge-type split: waves 0..3 (eg=0) own
// e in {0,1}, waves 4..7 (eg=1) own e in {2,3}. 80 KB LDS -> 2 blocks/CU,
// 16 waves/CU. __launch_bounds__(512,4): 4 waves/EU -> 128 regs/wave total
// (unified VGPR+AGPR). Round-6 spill root causes fixed: (a) node planes
// LDS-resident (was 32 persistent regs), (b) L1 adj fragments volatile
// (GVN held 64 regs across ut), (c) L2 ks-outer/edge-paired (GVN held
// ~80 regs of W2 fragments across mt).
__global__ __launch_bounds__(512, 4) void encoder_main(
    const float* __restrict__ adj, const float* __restrict__ node,
    const float* __restrict__ b1, const float* __restrict__ c1,
    const float* __restrict__ b2, const float* __restrict__ c2,
    const float* __restrict__ bi, const float* __restrict__ bj,
    const f16* __restrict__ wb, float* __restrict__ out)
{
  extern __shared__ unsigned char ldsb[];
  f16* adjh            = (f16*)(ldsb + ADJB_HI);
  unsigned char* adjl  = ldsb + ADJB_LO;
  f16* annh            = (f16*)(ldsb + ANNB_HI);
  unsigned char* annl  = ldsb + ANNB_LO;
  float* scr           = (float*)(ldsb + ANNB_HI);   // 16 KB f32 merge scratch
  f16* nodeH           = (f16*)(ldsb + PTB);          // persistent
  f16* nodeLo          = (f16*)(ldsb + PTB + 4096);   // persistent

  const int tid  = threadIdx.x;
  const int w    = tid >> 6;          // 0..7
  const int lane = tid & 63;
  const int q    = lane >> 4;
  const int l15  = lane & 15;
  const int eg   = w >> 2;            // edge group: e in {eg*2, eg*2+1}
  const int w4   = w & 3;             // u-slice index within group
  const int b    = blockIdx.x;
  const f32x4 z4 = {0.f, 0.f, 0.f, 0.f};

  // per-wave private transpose rows: ALL 8 waves in ANN_HI (dead there
  // during both PT liveness windows); PT_LO in ANN_LO as before.
  unsigned char* ptb = ldsb + ANNB_HI + w*2048;
  unsigned char* ptl = ldsb + ANNB_LO + w*1024;
  const int ptrow  = l15 * 128;
  const int ptlrow = l15 * 64;

  // node fragment loader: volatile (never cached in regs across uses)
  #define LOAD_NODE(mt, nh, nl) {                                   \
    int no_ = ((mt)*16 + l15)*32 + ((q ^ (l15 & 3)) * 8);           \
    nh = lds16v(&nodeH[no_]);                                       \
    nl = lds16v(&nodeLo[no_]); }

  // ---------------- stage: adjacency + node -> split LDS ----------------
  {
    const float* ap = adj + (size_t)b * 20480;
    #pragma unroll
    for (int i = 0; i < 4; ++i){
      int fu = tid + 512*i;                       // fu = (e*64 + m)*8 + uc
      int e = fu >> 9, m = (fu >> 3) & 63, uc = fu & 7;
      const float* p = ap + (m*64 + uc*8)*5 + e + 1;    // skip edge type 0
      float v[8], lo[8]; f16x8 hi;
      #pragma unroll
      for (int jj = 0; jj < 8; ++jj) v[jj] = p[jj*5];
      #pragma unroll
      for (int jj = 0; jj < 8; ++jj){
        f16 h = (f16)v[jj]; hi[jj] = h; lo[jj] = v[jj] - (float)h;
      }
      int off = e*4096 + m*64 + ((uc ^ (m & 7)) * 8);
      *(f16x8*)&adjh[off] = hi;
      enc8(&adjl[off], lo);
    }
    if (tid < 256){
      const float* np = node + (size_t)b * 2048 + (tid & 63)*32 + (tid >> 6)*8;
      float4 a = *(const float4*)np, c = *(const float4*)(np + 4);
      float v[8] = {a.x, a.y, a.z, a.w, c.x, c.y, c.z, c.w};
      f16x8 hi, lo;
      #pragma unroll
      for (int jj = 0; jj < 8; ++jj){
        f16 h = (f16)v[jj]; hi[jj] = h; lo[jj] = (f16)(v[jj] - (float)h);
      }
      int n = tid & 63, un = tid >> 6;
      *(f16x8*)&nodeH [n*32 + ((un ^ (n & 3)) * 8)] = hi;
      *(f16x8*)&nodeLo[n*32 + ((un ^ (n & 3)) * 8)] = lo;
    }
  }
  __syncthreads();   // S: staging complete

  // ============ layer 1: h1 = tanh(sum_e A_e(node@W1+b1) + node@V1 + c1) ============
  f32x4 acc1[4][2];
  #pragma unroll
  for (int mt = 0; mt < 4; ++mt){ acc1[mt][0] = z4; acc1[mt][1] = z4; }

  #pragma unroll
  for (int i = 0; i < 2; ++i){
    const int e = eg*2 + i;
    #pragma unroll
    for (int ut = 0; ut < 2; ++ut){
      const int u = w4*32 + ut*16 + l15;
      f16x8 wh = *(const f16x8*)&wb[W1T_HI + (e*128 + u)*32 + q*8];
      f16x8 wl = *(const f16x8*)&wb[W1T_LO + (e*128 + u)*32 + q*8];
      float bias = b1[e*128 + u];
      #pragma unroll
      for (int mt = 0; mt < 4; ++mt){
        f16x8 nh, nl; LOAD_NODE(mt, nh, nl);
        f32x4 pf = mfma16(nh, wh, z4);
        pf = mfma16(nl, wh, pf);
        pf = mfma16(nh, wl, pf);
        f16x4 ph; float lo4[4];
        #pragma unroll
        for (int r = 0; r < 4; ++r){
          float v = pf[r] + bias;
          f16 h = (f16)v; ph[r] = h; lo4[r] = v - (float)h;
        }
        int unit = ((mt*2 + (q >> 1)) ^ (l15 & 7));      // n0 = mt*16+q*4
        *(f16x4*)(ptb + ptrow + unit*16 + (q & 1)*8) = ph;       // PT_HI[u_loc][n]
        *(u32*)(ptl + ptlrow + unit*8 + (q & 1)*4) = enc4(lo4);  // PT_LO
      }
      // adjacency fragments: volatile (addresses are ut-invariant; plain
      // loads were GVN-held across both ut iterations = 64 regs = spill)
      #pragma unroll
      for (int ks = 0; ks < 2; ++ks){
        int pu = ((ks*4 + q) ^ (l15 & 7));
        f16x8 bph = *(const f16x8*)(ptb + ptrow + pu*16);
        f16x8 bpl = dec8(ptl + ptlrow + pu*8);
        #pragma unroll
        for (int mt = 0; mt < 4; ++mt){
          int off = e*4096 + (mt*16 + l15)*64 + (((ks*4 + q) ^ (l15 & 7)) * 8);
          f16x8 ah = lds16v(&adjh[off]);
          f16x8 al = dec8v(&adjl[off]);
          acc1[mt][ut] = mfma16(ah, bph, acc1[mt][ut]);
          acc1[mt][ut] = mfma16(al, bph, acc1[mt][ut]);
          acc1[mt][ut] = mfma16(ah, bpl, acc1[mt][ut]);
        }
      }
    }
  }
  __syncthreads();   // B0: all PT/PT_LO reads done; scr may overlay PT

  // merge1 in two u-halves (scr is only 16 KB now): eg0 folds V1 term
  // while eg1 waves 4,5 publish u in [0,64); then waves 6,7 publish
  // u in [64,128). scr swizzle: ul ^ ((n&4)<<2) -> 2-way max (free).
  if (eg == 0){
    #pragma unroll
    for (int ut = 0; ut < 2; ++ut){
      const int u = w4*32 + ut*16 + l15;
      f16x8 wh = *(const f16x8*)&wb[V1T_HI + u*32 + q*8];
      f16x8 wl = *(const f16x8*)&wb[V1T_LO + u*32 + q*8];
      #pragma unroll
      for (int mt = 0; mt < 4; ++mt){
        f16x8 nh, nl; LOAD_NODE(mt, nh, nl);
        acc1[mt][ut] = mfma16(nh, wh, acc1[mt][ut]);
        acc1[mt][ut] = mfma16(nl, wh, acc1[mt][ut]);
        acc1[mt][ut] = mfma16(nh, wl, acc1[mt][ut]);
      }
    }
  } else if (w4 < 2){
    #pragma unroll
    for (int mt = 0; mt < 4; ++mt)
      #pragma unroll
      for (int ut = 0; ut < 2; ++ut)
        #pragma unroll
        for (int r = 0; r < 4; ++r){
          int n = mt*16 + q*4 + r;
          int ul = w4*32 + ut*16 + l15;                  // [0,64)
          scr[n*64 + (ul ^ ((n & 4) << 2))] = acc1[mt][ut][r];
        }
  }
  __syncthreads();   // B1: half0 ready
  if (eg == 0 && w4 < 2){
    #pragma unroll
    for (int mt = 0; mt < 4; ++mt)
      #pragma unroll
      for (int ut = 0; ut < 2; ++ut)
        #pragma unroll
        for (int r = 0; r < 4; ++r){
          int n = mt*16 + q*4 + r;
          int ul = w4*32 + ut*16 + l15;
          acc1[mt][ut][r] += scr[n*64 + (ul ^ ((n & 4) << 2))];
        }
  }
  __syncthreads();   // B1b: half0 consumed
  if (eg == 1 && w4 >= 2){
    #pragma unroll
    for (int mt = 0; mt < 4; ++mt)
      #pragma unroll
      for (int ut = 0; ut < 2; ++ut)
        #pragma unroll
        for (int r = 0; r < 4; ++r){
          int n = mt*16 + q*4 + r;
          int ul = (w4 - 2)*32 + ut*16 + l15;            // [0,64) local
          scr[n*64 + (ul ^ ((n & 4) << 2))] = acc1[mt][ut][r];
        }
  }
  __syncthreads();   // B1c: half1 ready
  if (eg == 0 && w4 >= 2){
    #pragma unroll
    for (int mt = 0; mt < 4; ++mt)
      #pragma unroll
      for (int ut = 0; ut < 2; ++ut)
        #pragma unroll
        for (int r = 0; r < 4; ++r){
          int n = mt*16 + q*4 + r;
          int ul = (w4 - 2)*32 + ut*16 + l15;
          acc1[mt][ut][r] += scr[n*64 + (ul ^ ((n & 4) << 2))];
        }
  }
  __syncthreads();   // B2: scr dead; ann writes may begin
  if (eg == 0){
    #pragma unroll
    for (int ut = 0; ut < 2; ++ut){
      const int u = w4*32 + ut*16 + l15;
      float cv = c1[u];
      #pragma unroll
      for (int mt = 0; mt < 4; ++mt)
        #pragma unroll
        for (int r = 0; r < 4; ++r){
          float h = fast_tanh(acc1[mt][ut][r] + cv);
          f16 hh = (f16)h;
          int row = mt*16 + q*4 + r;
          int unit = ((u >> 3) ^ (row & 7));
          annh[row*128 + unit*8 + (u & 7)] = hh;                   // h1 cols 0..127
          annl[row*128 + unit*8 + (u & 7)] = enc1(h - (float)hh);
        }
    }
  }
  __syncthreads();   // B3: h1 ready

  // ============ layer 2: h2 = tanh(sum_e A_e(ann@W2+b2) + node@V2 + c2) ============
  // ks-outer, both edge types paired: every ann fragment is loaded exactly
  // once (no GVN-held W2/ann fragments across mt).
  const int u2 = w4*16 + l15;
  const int e0 = eg*2, e1 = eg*2 + 1;
  const f16* w2h0 = &wb[W2T_HI + (e0*64 + u2)*160];
  const f16* w2l0 = &wb[W2T_LO + (e0*64 + u2)*160];
  const f16* w2h1 = &wb[W2T_HI + (e1*64 + u2)*160];
  const f16* w2l1 = &wb[W2T_LO + (e1*64 + u2)*160];
  f32x4 qf[2][4];
  {
    f16x8 wA = *(const f16x8*)&w2h0[128 + q*8];    // node part k=128..159
    f16x8 wB = *(const f16x8*)&w2l0[128 + q*8];
    f16x8 wC = *(const f16x8*)&w2h1[128 + q*8];
    f16x8 wD = *(const f16x8*)&w2l1[128 + q*8];
    #pragma unroll
    for (int mt = 0; mt < 4; ++mt){
      f16x8 nh, nl; LOAD_NODE(mt, nh, nl);
      f32x4 t0 = mfma16(nh, wA, z4);
      t0 = mfma16(nl, wA, t0);
      t0 = mfma16(nh, wB, t0);
      f32x4 t1 = mfma16(nh, wC, z4);
      t1 = mfma16(nl, wC, t1);
      t1 = mfma16(nh, wD, t1);
      qf[0][mt] = t0; qf[1][mt] = t1;
    }
  }
  #pragma unroll
  for (int ks = 0; ks < 4; ++ks){
    f16x8 wA = *(const f16x8*)&w2h0[ks*32 + q*8];
    f16x8 wB = *(const f16x8*)&w2l0[ks*32 + q*8];
    f16x8 wC = *(const f16x8*)&w2h1[ks*32 + q*8];
    f16x8 wD = *(const f16x8*)&w2l1[ks*32 + q*8];
    #pragma unroll
    for (int mt = 0; mt < 4; ++mt){
      int off = (mt*16 + l15)*128 + (((ks*4 + q) ^ (l15 & 7)) * 8);
      f16x8 axh = *(const f16x8*)&annh[off];
      f16x8 axl = dec8(&annl[off]);
      qf[0][mt] = mfma16(axh, wA, qf[0][mt]);
      qf[0][mt] = mfma16(axl, wA, qf[0][mt]);
      qf[0][mt] = mfma16(axh, wB, qf[0][mt]);
      qf[1][mt] = mfma16(axh, wC, qf[1][mt]);
      qf[1][mt] = mfma16(axl, wC, qf[1][mt]);
      qf[1][mt] = mfma16(axh, wD, qf[1][mt]);
    }
  }
  __syncthreads();   // B4: ann reads done before QT overlays ann

  f32x4 acc2[4];
  #pragma unroll
  for (int mt = 0; mt < 4; ++mt) acc2[mt] = z4;
  #pragma unroll
  for (int i = 0; i < 2; ++i){
    const int e = eg*2 + i;
    float bias = b2[e*64 + u2];
    #pragma unroll
    for (int mt = 0; mt < 4; ++mt){
      f16x4 ph; float lo4[4];
      #pragma unroll
      for (int r = 0; r < 4; ++r){
        float v = qf[i][mt][r] + bias;
        f16 h = (f16)v; ph[r] = h; lo4[r] = v - (float)h;
      }
      int unit = ((mt*2 + (q >> 1)) ^ (l15 & 7));
      *(f16x4*)(ptb + ptrow + unit*16 + (q & 1)*8) = ph;       // QT_HI[u_loc][n]
      *(u32*)(ptl + ptlrow + unit*8 + (q & 1)*4) = enc4(lo4);  // QT_LO
    }
    #pragma unroll
    for (int ks = 0; ks < 2; ++ks){
      int pu = ((ks*4 + q) ^ (l15 & 7));
      f16x8 bph = *(const f16x8*)(ptb + ptrow + pu*16);
      f16x8 bpl = dec8(ptl + ptlrow + pu*8);
      #pragma unroll
      for (int mt = 0; mt < 4; ++mt){
        int off = e*4096 + (mt*16 + l15)*64 + (((ks*4 + q) ^ (l15 & 7)) * 8);
        f16x8 ah = *(const f16x8*)&adjh[off];
        f16x8 al = dec8(&adjl[off]);
        acc2[mt] = mfma16(ah, bph, acc2[mt]);
        acc2[mt] = mfma16(al, bph, acc2[mt]);
        acc2[mt] = mfma16(ah, bpl, acc2[mt]);
      }
    }
  }
  // B4b: scr2 (16 KB @ ANN_HI) overlays ALL waves' QT_HI buffers — wait
  // for every wave's QT reads (round-1 lesson).
  __syncthreads();
  if (eg == 0){
    f16x8 wh = *(const f16x8*)&wb[V2T_HI + u2*32 + q*8];
    f16x8 wl = *(const f16x8*)&wb[V2T_LO + u2*32 + q*8];
    #pragma unroll
    for (int mt = 0; mt < 4; ++mt){
      f16x8 nh, nl; LOAD_NODE(mt, nh, nl);
      acc2[mt] = mfma16(nh, wh, acc2[mt]);
      acc2[mt] = mfma16(nl, wh, acc2[mt]);
      acc2[mt] = mfma16(nh, wl, acc2[mt]);
    }
  } else {
    #pragma unroll
    for (int mt = 0; mt < 4; ++mt)
      #pragma unroll
      for (int r = 0; r < 4; ++r){
        int n = mt*16 + q*4 + r;
        scr[n*64 + (u2 ^ ((n & 4) << 2))] = acc2[mt][r];
      }
  }
  __syncthreads();   // B5: scratch2 ready
  if (eg == 0){
    #pragma unroll
    for (int mt = 0; mt < 4; ++mt)
      #pragma unroll
      for (int r = 0; r < 4; ++r){
        int n = mt*16 + q*4 + r;
        acc2[mt][r] += scr[n*64 + (u2 ^ ((n & 4) << 2))];
      }
  }
  __syncthreads();   // B6: scratch2 reads done before h2 writes overlay it
  if (eg == 0){
    float cv = c2[u2];
    const int uc = 64 + u2;
    #pragma unroll
    for (int mt = 0; mt < 4; ++mt)
      #pragma unroll
      for (int r = 0; r < 4; ++r){
        float h = fast_tanh(acc2[mt][r] + cv);
        f16 hh = (f16)h;
        int row = mt*16 + q*4 + r;
        int unit = ((uc >> 3) ^ (row & 7));
        annh[row*128 + unit*8 + (uc & 7)] = hh;                  // h2 cols 64..127
        annl[row*128 + unit*8 + (uc & 7)] = enc1(h - (float)hh);
      }
  }
  __syncthreads();   // B7: h2 ready

  // ============ aggregation: out = tanh(sum_n sigmoid(.)·tanh(.)) ============
  // ks-outer, weights streamed (16 transient regs), accumulate in agprs.
  const int ua = w*16 + l15;                      // 8 waves x 16 = 128
  float bib = bi[ua], bjb = bj[ua];
  f32x4 iacc[4], jacc[4];
  #pragma unroll
  for (int mt = 0; mt < 4; ++mt){ iacc[mt] = z4; jacc[mt] = z4; }
  #pragma unroll
  for (int ks = 0; ks < 3; ++ks){
    f16x8 wih = *(const f16x8*)&wb[WIT_HI + ua*96 + ks*32 + q*8];
    f16x8 wil = *(const f16x8*)&wb[WIT_LO + ua*96 + ks*32 + q*8];
    f16x8 wjh = *(const f16x8*)&wb[WJT_HI + ua*96 + ks*32 + q*8];
    f16x8 wjl = *(const f16x8*)&wb[WJT_LO + ua*96 + ks*32 + q*8];
    if (ks < 2){
      #pragma unroll
      for (int mt = 0; mt < 4; ++mt){
        int off = (mt*16 + l15)*128 + (((8 + ks*4 + q) ^ (l15 & 7)) * 8);
        f16x8 gh = *(const f16x8*)&annh[off];
        f16x8 gl = dec8(&annl[off]);
        iacc[mt] = mfma16(gh, wih, iacc[mt]);
        iacc[mt] = mfma16(gl, wih, iacc[mt]);
        iacc[mt] = mfma16(gh, wil, iacc[mt]);
        jacc[mt] = mfma16(gh, wjh, jacc[mt]);
        jacc[mt] = mfma16(gl, wjh, jacc[mt]);
        jacc[mt] = mfma16(gh, wjl, jacc[mt]);
      }
    } else {
      #pragma unroll
      for (int mt = 0; mt < 4; ++mt){
        f16x8 nh, nl; LOAD_NODE(mt, nh, nl);
        iacc[mt] = mfma16(nh, wih, iacc[mt]);
        iacc[mt] = mfma16(nl, wih, iacc[mt]);
        iacc[mt] = mfma16(nh, wil, iacc[mt]);
        jacc[mt] = mfma16(nh, wjh, jacc[mt]);
        jacc[mt] = mfma16(nl, wjh, jacc[mt]);
        jacc[mt] = mfma16(nh, wjl, jacc[mt]);
      }
    }
  }
  float s = 0.f;
  #pragma unroll
  for (int mt = 0; mt < 4; ++mt)
    #pragma unroll
    for (int r = 0; r < 4; ++r)
      s += fast_sigmoid(iacc[mt][r] + bib) * fast_tanh(jacc[mt][r] + bjb);
  s += __shfl_xor(s, 16);
  s += __shfl_xor(s, 32);
  if (q == 0) out[(size_t)b*128 + ua] = fast_tanh(s);
  #undef LOAD_NODE
}

extern "C" void kernel_launch(void* const* d_in, const int* in_sizes, int n_in,
                              void* d_out, int out_size, void* d_ws, size_t ws_size,
                              hipStream_t stream) {
  (void)in_sizes; (void)n_in; (void)out_size; (void)ws_size;
  const float* adj  = (const float*)d_in[0];
  // d_in[1] = hidden (zeros, rank-2): unused by the reference path
  const float* node = (const float*)d_in[2];
  const float* W1   = (const float*)d_in[3];
  const float* b1   = (const float*)d_in[4];
  const float* V1   = (const float*)d_in[5];
  const float* c1   = (const float*)d_in[6];
  const float* W2   = (const float*)d_in[7];
  const float* b2   = (const float*)d_in[8];
  const float* V2   = (const float*)d_in[9];
  const float* c2   = (const float*)d_in[10];
  const float* Wi   = (const float*)d_in[11];
  const float* bi   = (const float*)d_in[12];
  const float* Wj   = (const float*)d_in[13];
  const float* bj   = (const float*)d_in[14];
  f16* wb    = (f16*)d_ws;
  float* out = (float*)d_out;

  hipFuncSetAttribute((const void*)encoder_main,
                      hipFuncAttributeMaxDynamicSharedMemorySize, LDS_BYTES);

  prep_weights<<<(WS_SRC + 255) / 256, 256, 0, stream>>>(W1, V1, W2, V2, Wi, Wj, wb);
  encoder_main<<<2048, 512, LDS_BYTES, stream>>>(adj, node, b1, c1, b2, c2, bi, bj, wb, out);
}

// Round 8
// 433.442 us; speedup vs baseline: 1.2710x; 1.2710x over previous
//
#include <hip/hip_runtime.h>

typedef _Float16 f16;
typedef f16  f16x8 __attribute__((ext_vector_type(8)));
typedef f16  f16x4 __attribute__((ext_vector_type(4)));
typedef float f32x4 __attribute__((ext_vector_type(4)));
typedef unsigned int u32;

// ---- d_ws layout (f16 elems): hi/lo split weights, 352,256 B ----
#define W1T_HI 0        // [4][128][32]  W1T[e][u][f]
#define W1T_LO 16384
#define V1T_HI 32768    // [128][32]
#define V1T_LO 36864
#define W2T_HI 40960    // [4][64][160]  W2T[e][u][k], k = [h1(128), node(32)]
#define W2T_LO 81920
#define V2T_HI 122880   // [64][32]
#define V2T_LO 124928
#define WIT_HI 126976   // [128][96]     WiT[ua][k], k = [h2(64), node(32)]
#define WIT_LO 139264
#define WJT_HI 151552
#define WJT_LO 163840
#define WS_SRC 88064

// ---- dynamic LDS: 131,072 B = 128 KB; 1024-thread block -> 1 block/CU,
// 16 waves/CU. Dedicated regions (no ANN overlays):
//   ADJ_HI/LO, ANN_HI/LO, NODE planes, PT_HI/LO for 16 waves.
// Overlays ONLY in the PT region (dead windows, barrier-guarded):
//   scr  (L1 merge, f32[64][128] = 32K)   @ PT_HI
//   scr2 (L2 merge, 3 x f32[64][64]=16K)  @ PT_HI(+0,+16K) and PT_LO
//   pex  (agg partial exchange, 1K)       @ PT_HI
#define ADJB_HI 0        // f16 [4][64][64], XOR swizzle (unit8 ^ (m&7))  32768 B
#define ADJB_LO 32768    // u8  [4][64][64], same swizzle                16384 B
#define ANNB_HI 49152    // f16 [64][128]: h1; h2 overlays cols 64..127  16384 B
#define ANNB_LO 65536    // u8  [64][128]                                 8192 B
#define NODEB   73728    // f16 nodeH[64][32] + nodeLo[64][32]            8192 B
#define PTHB    81920    // 16 waves x 2048 B PT/QT_HI                   32768 B
#define PTLB    114688   // 16 waves x 1024 B PT/QT_LO                   16384 B
#define LDS_BYTES 131072

__device__ __forceinline__ f32x4 mfma16(f16x8 a, f16x8 b, f32x4 c){
  return __builtin_amdgcn_mfma_f32_16x16x32_f16(a, b, c, 0, 0, 0);
}
// rcp-based activations: exact at +-inf (rcp(inf)=0), ~6 VALU ops.
__device__ __forceinline__ float fast_tanh(float x){
  float e = __expf(2.f * x);
  return 1.f - 2.f * __builtin_amdgcn_rcpf(e + 1.f);
}
__device__ __forceinline__ float fast_sigmoid(float x){
  return __builtin_amdgcn_rcpf(1.f + __expf(-x));
}

// ---- 8-bit lo-plane codec: byte = top 8 bits of f16(lo), RTN via +0x80.
// Decode = byte into HIGH byte of f16 lane -> 4x v_perm_b32 per 8 elems.
__device__ __forceinline__ unsigned char enc1(float lo){
  f16 h = (f16)lo;
  unsigned short u = __builtin_bit_cast(unsigned short, h);
  return (unsigned char)(((u32)u + 0x80u) >> 8);
}
__device__ __forceinline__ void enc8(unsigned char* p, const float* lo){
  u32 a = 0, b = 0;
  #pragma unroll
  for (int j = 0; j < 4; ++j) a |= (u32)enc1(lo[j]) << (8*j);
  #pragma unroll
  for (int j = 0; j < 4; ++j) b |= (u32)enc1(lo[4+j]) << (8*j);
  uint2 v = {a, b};
  *(uint2*)p = v;
}
__device__ __forceinline__ u32 enc4(const float* lo){
  return (u32)enc1(lo[0]) | ((u32)enc1(lo[1]) << 8)
       | ((u32)enc1(lo[2]) << 16) | ((u32)enc1(lo[3]) << 24);
}
__device__ __forceinline__ f16x8 dec8(const unsigned char* p){
  uint2 d = *(const uint2*)p;
  u32 w[4];
  w[0] = __builtin_amdgcn_perm(0u, d.x, 0x010c000cu);  // [0]=0,[1]=b0,[2]=0,[3]=b1
  w[1] = __builtin_amdgcn_perm(0u, d.x, 0x030c020cu);  // b2, b3
  w[2] = __builtin_amdgcn_perm(0u, d.y, 0x010c000cu);  // b4, b5
  w[3] = __builtin_amdgcn_perm(0u, d.y, 0x030c020cu);  // b6, b7
  f16x8 r; __builtin_memcpy(&r, w, 16);
  return r;
}

__global__ void prep_weights(const float* __restrict__ W1, const float* __restrict__ V1,
                             const float* __restrict__ W2, const float* __restrict__ V2,
                             const float* __restrict__ Wi, const float* __restrict__ Wj,
                             f16* __restrict__ ws){
  int i = blockIdx.x * 256 + threadIdx.x;
  if (i >= WS_SRC) return;
  float v; int hi_off, lo_off, idx;
  int j = i;
  if (j < 16384){ int e = j >> 12, u = (j >> 5) & 127, f = j & 31;
    v = W1[(e*32 + f)*128 + u]; hi_off = W1T_HI; lo_off = W1T_LO; idx = j; }
  else if ((j -= 16384) < 4096){ int u = j >> 5, f = j & 31;
    v = V1[f*128 + u]; hi_off = V1T_HI; lo_off = V1T_LO; idx = j; }
  else if ((j -= 4096) < 40960){ int e = j / 10240, r = j % 10240, u = r / 160, k = r % 160;
    v = W2[e*10240 + k*64 + u]; hi_off = W2T_HI; lo_off = W2T_LO; idx = j; }
  else if ((j -= 40960) < 2048){ int u = j >> 5, f = j & 31;
    v = V2[f*64 + u]; hi_off = V2T_HI; lo_off = V2T_LO; idx = j; }
  else if ((j -= 2048) < 12288){ int ua = j / 96, k = j % 96;
    v = Wi[k*128 + ua]; hi_off = WIT_HI; lo_off = WIT_LO; idx = j; }
  else { j -= 12288; int ua = j / 96, k = j % 96;
    v = Wj[k*128 + ua]; hi_off = WJT_HI; lo_off = WJT_LO; idx = j; }
  f16 h = (f16)v;
  ws[hi_off + idx] = h;
  ws[lo_off + idx] = (f16)(v - (float)h);
}

// one block = one batch; 16 waves (1024 thr), 1 block/CU (128 KB LDS),
// 16 waves/CU = 50% occupancy cap. Per-wave state HALVED vs the 8-wave
// variants so the whole kernel fits the 128-reg/wave budget with ZERO
// spill (rounds 2-7: 8-wave blocks needed ~156 regs -> 64-arch pin +
// 230-950 MB scratch traffic):
//   L1: eg=w>>3 owns 2 edge types, u-slice (w&7)*16 -> acc1[4] only.
//   L2: each wave owns ONE edge type e=eg*2+((w>>2)&1), u2=(w&3)*16.
//   agg: ua=(w&7)*16, 2 mt rows each; cross-wave partial via LDS.
__global__ __launch_bounds__(1024, 4) void encoder_main(
    const float* __restrict__ adj, const float* __restrict__ node,
    const float* __restrict__ b1, const float* __restrict__ c1,
    const float* __restrict__ b2, const float* __restrict__ c2,
    const float* __restrict__ bi, const float* __restrict__ bj,
    const f16* __restrict__ wb, float* __restrict__ out)
{
  extern __shared__ unsigned char ldsb[];
  f16* adjh            = (f16*)(ldsb + ADJB_HI);
  unsigned char* adjl  = ldsb + ADJB_LO;
  f16* annh            = (f16*)(ldsb + ANNB_HI);
  unsigned char* annl  = ldsb + ANNB_LO;
  f16* nodeH           = (f16*)(ldsb + NODEB);
  f16* nodeLo          = (f16*)(ldsb + NODEB + 4096);
  float* scr           = (float*)(ldsb + PTHB);      // L1 merge [64][128] f32

  const int tid  = threadIdx.x;
  const int w    = tid >> 6;          // 0..15
  const int lane = tid & 63;
  const int q    = lane >> 4;
  const int l15  = lane & 15;
  const int eg   = w >> 3;            // L1 edge group: e in {2eg, 2eg+1}
  const int b    = blockIdx.x;
  const f32x4 z4 = {0.f, 0.f, 0.f, 0.f};

  // per-wave private transpose rows: 16 x 128 B hi + 16 x 64 B lo
  unsigned char* ptb = ldsb + PTHB + w*2048;
  unsigned char* ptl = ldsb + PTLB + w*1024;
  const int ptrow  = l15 * 128;
  const int ptlrow = l15 * 64;

  // ---------------- stage: adjacency + node -> split LDS ----------------
  {
    const float* ap = adj + (size_t)b * 20480;
    #pragma unroll
    for (int i = 0; i < 2; ++i){
      int fu = tid + 1024*i;                      // fu = (e*64 + m)*8 + uc
      int e = fu >> 9, m = (fu >> 3) & 63, uc = fu & 7;
      const float* p = ap + (m*64 + uc*8)*5 + e + 1;    // skip edge type 0
      float v[8], lo[8]; f16x8 hi;
      #pragma unroll
      for (int jj = 0; jj < 8; ++jj) v[jj] = p[jj*5];
      #pragma unroll
      for (int jj = 0; jj < 8; ++jj){
        f16 h = (f16)v[jj]; hi[jj] = h; lo[jj] = v[jj] - (float)h;
      }
      int off = e*4096 + m*64 + ((uc ^ (m & 7)) * 8);
      *(f16x8*)&adjh[off] = hi;
      enc8(&adjl[off], lo);
    }
    if (tid < 256){
      const float* np = node + (size_t)b * 2048 + (tid & 63)*32 + (tid >> 6)*8;
      float4 a = *(const float4*)np, c = *(const float4*)(np + 4);
      float v[8] = {a.x, a.y, a.z, a.w, c.x, c.y, c.z, c.w};
      f16x8 hi, lo;
      #pragma unroll
      for (int jj = 0; jj < 8; ++jj){
        f16 h = (f16)v[jj]; hi[jj] = h; lo[jj] = (f16)(v[jj] - (float)h);
      }
      int n = tid & 63, un = tid >> 6;
      *(f16x8*)&nodeH [n*32 + ((un ^ (n & 3)) * 8)] = hi;
      *(f16x8*)&nodeLo[n*32 + ((un ^ (n & 3)) * 8)] = lo;
    }
  }
  __syncthreads();   // S: staging complete

  // node A-frags hi+lo in registers for the whole kernel (32 regs)
  f16x8 anh[4], anl[4];
  #pragma unroll
  for (int mt = 0; mt < 4; ++mt){
    anh[mt] = *(const f16x8*)&nodeH [(mt*16 + l15)*32 + ((q ^ (l15 & 3)) * 8)];
    anl[mt] = *(const f16x8*)&nodeLo[(mt*16 + l15)*32 + ((q ^ (l15 & 3)) * 8)];
  }

  // ============ layer 1: h1 = tanh(sum_e A_e(node@W1+b1) + node@V1 + c1) ============
  const int u1 = (w & 7)*16 + l15;                // wave's u-slice (one only)
  f32x4 acc1[4];
  #pragma unroll
  for (int mt = 0; mt < 4; ++mt) acc1[mt] = z4;

  #pragma unroll
  for (int i = 0; i < 2; ++i){
    const int e = eg*2 + i;
    f16x8 wh = *(const f16x8*)&wb[W1T_HI + (e*128 + u1)*32 + q*8];
    f16x8 wl = *(const f16x8*)&wb[W1T_LO + (e*128 + u1)*32 + q*8];
    float bias = b1[e*128 + u1];
    #pragma unroll
    for (int mt = 0; mt < 4; ++mt){
      f32x4 pf = mfma16(anh[mt], wh, z4);
      pf = mfma16(anl[mt], wh, pf);
      pf = mfma16(anh[mt], wl, pf);
      f16x4 ph; float lo4[4];
      #pragma unroll
      for (int r = 0; r < 4; ++r){
        float v = pf[r] + bias;
        f16 h = (f16)v; ph[r] = h; lo4[r] = v - (float)h;
      }
      int unit = ((mt*2 + (q >> 1)) ^ (l15 & 7));        // n0 = mt*16+q*4
      *(f16x4*)(ptb + ptrow + unit*16 + (q & 1)*8) = ph;       // PT_HI[u_loc][n]
      *(u32*)(ptl + ptlrow + unit*8 + (q & 1)*4) = enc4(lo4);  // PT_LO
    }
    #pragma unroll
    for (int ks = 0; ks < 2; ++ks){
      int pu = ((ks*4 + q) ^ (l15 & 7));
      f16x8 bph = *(const f16x8*)(ptb + ptrow + pu*16);
      f16x8 bpl = dec8(ptl + ptlrow + pu*8);
      #pragma unroll
      for (int mt = 0; mt < 4; ++mt){
        int off = e*4096 + (mt*16 + l15)*64 + (((ks*4 + q) ^ (l15 & 7)) * 8);
        f16x8 ah = *(const f16x8*)&adjh[off];
        f16x8 al = dec8(&adjl[off]);
        acc1[mt] = mfma16(ah, bph, acc1[mt]);
        acc1[mt] = mfma16(al, bph, acc1[mt]);
        acc1[mt] = mfma16(ah, bpl, acc1[mt]);
      }
    }
  }
  __syncthreads();   // B0: ALL waves' PT reads done (scr overlays PT_HI)

  // merge1: eg1 publishes to scr; eg0 folds V1 term in parallel.
  // scr swizzle u ^ ((n&4)<<2): 2-way max bank alias (free), bijective.
  if (eg == 1){
    #pragma unroll
    for (int mt = 0; mt < 4; ++mt)
      #pragma unroll
      for (int r = 0; r < 4; ++r){
        int n = mt*16 + q*4 + r;
        scr[n*128 + (u1 ^ ((n & 4) << 2))] = acc1[mt][r];
      }
  } else {
    f16x8 wh = *(const f16x8*)&wb[V1T_HI + u1*32 + q*8];
    f16x8 wl = *(const f16x8*)&wb[V1T_LO + u1*32 + q*8];
    #pragma unroll
    for (int mt = 0; mt < 4; ++mt){
      acc1[mt] = mfma16(anh[mt], wh, acc1[mt]);
      acc1[mt] = mfma16(anl[mt], wh, acc1[mt]);
      acc1[mt] = mfma16(anh[mt], wl, acc1[mt]);
    }
  }
  __syncthreads();   // B1: scr ready
  if (eg == 0){
    float cv = c1[u1];
    #pragma unroll
    for (int mt = 0; mt < 4; ++mt)
      #pragma unroll
      for (int r = 0; r < 4; ++r){
        int n = mt*16 + q*4 + r;
        float h = fast_tanh(acc1[mt][r] + scr[n*128 + (u1 ^ ((n & 4) << 2))] + cv);
        f16 hh = (f16)h;
        int unit = ((u1 >> 3) ^ (n & 7));
        annh[n*128 + unit*8 + (u1 & 7)] = hh;                    // h1 cols 0..127
        annl[n*128 + unit*8 + (u1 & 7)] = enc1(h - (float)hh);
      }
  }
  __syncthreads();   // B3: h1 ready; eg0 scr reads done (PT reusable as QT)

  // ============ layer 2: h2 = tanh(sum_e A_e(ann@W2+b2) + node@V2 + c2) ============
  // each wave owns ONE edge type and one 16-wide u2 slice.
  const int e2 = eg*2 + ((w >> 2) & 1);
  const int u2 = (w & 3)*16 + l15;
  const f16* w2h = &wb[W2T_HI + (e2*64 + u2)*160];
  const f16* w2l = &wb[W2T_LO + (e2*64 + u2)*160];
  f32x4 qf[4];
  {
    f16x8 wnh = *(const f16x8*)&w2h[128 + q*8];    // node part k=128..159
    f16x8 wnl = *(const f16x8*)&w2l[128 + q*8];
    #pragma unroll
    for (int mt = 0; mt < 4; ++mt){
      f32x4 t = mfma16(anh[mt], wnh, z4);
      t = mfma16(anl[mt], wnh, t);
      t = mfma16(anh[mt], wnl, t);
      qf[mt] = t;
    }
  }
  #pragma unroll
  for (int ks = 0; ks < 4; ++ks){
    f16x8 wh = *(const f16x8*)&w2h[ks*32 + q*8];
    f16x8 wl = *(const f16x8*)&w2l[ks*32 + q*8];
    #pragma unroll
    for (int mt = 0; mt < 4; ++mt){
      int off = (mt*16 + l15)*128 + (((ks*4 + q) ^ (l15 & 7)) * 8);
      f16x8 axh = *(const f16x8*)&annh[off];
      f16x8 axl = dec8(&annl[off]);
      qf[mt] = mfma16(axh, wh, qf[mt]);
      qf[mt] = mfma16(axl, wh, qf[mt]);
      qf[mt] = mfma16(axh, wl, qf[mt]);
    }
  }
  // QT transpose + A·Q accumulate
  f32x4 acc2[4];
  #pragma unroll
  for (int mt = 0; mt < 4; ++mt) acc2[mt] = z4;
  {
    float bias = b2[e2*64 + u2];
    #pragma unroll
    for (int mt = 0; mt < 4; ++mt){
      f16x4 ph; float lo4[4];
      #pragma unroll
      for (int r = 0; r < 4; ++r){
        float v = qf[mt][r] + bias;
        f16 h = (f16)v; ph[r] = h; lo4[r] = v - (float)h;
      }
      int unit = ((mt*2 + (q >> 1)) ^ (l15 & 7));
      *(f16x4*)(ptb + ptrow + unit*16 + (q & 1)*8) = ph;       // QT_HI[u_loc][n]
      *(u32*)(ptl + ptlrow + unit*8 + (q & 1)*4) = enc4(lo4);  // QT_LO
    }
    #pragma unroll
    for (int ks = 0; ks < 2; ++ks){
      int pu = ((ks*4 + q) ^ (l15 & 7));
      f16x8 bph = *(const f16x8*)(ptb + ptrow + pu*16);
      f16x8 bpl = dec8(ptl + ptlrow + pu*8);
      #pragma unroll
      for (int mt = 0; mt < 4; ++mt){
        int off = e2*4096 + (mt*16 + l15)*64 + (((ks*4 + q) ^ (l15 & 7)) * 8);
        f16x8 ah = *(const f16x8*)&adjh[off];
        f16x8 al = dec8(&adjl[off]);
        acc2[mt] = mfma16(ah, bph, acc2[mt]);
        acc2[mt] = mfma16(al, bph, acc2[mt]);
        acc2[mt] = mfma16(ah, bpl, acc2[mt]);
      }
    }
  }
  // B4b: scr2 overlays PT_HI+PT_LO (= every wave's QT buffers) — wait for
  // ALL waves' QT reads (round-1 lesson).
  __syncthreads();

  // merge2 (4-way): e2=1,2,3 waves publish to 3 scratch planes; e2=0
  // waves fold V2 in parallel, then read+sum after B5.
  if (e2 == 0){
    f16x8 wh = *(const f16x8*)&wb[V2T_HI + u2*32 + q*8];
    f16x8 wl = *(const f16x8*)&wb[V2T_LO + u2*32 + q*8];
    #pragma unroll
    for (int mt = 0; mt < 4; ++mt){
      acc2[mt] = mfma16(anh[mt], wh, acc2[mt]);
      acc2[mt] = mfma16(anl[mt], wh, acc2[mt]);
      acc2[mt] = mfma16(anh[mt], wl, acc2[mt]);
    }
  } else {
    float* s2 = (e2 == 1) ? (float*)(ldsb + PTHB)
              : (e2 == 2) ? (float*)(ldsb + PTHB + 16384)
                          : (float*)(ldsb + PTLB);
    #pragma unroll
    for (int mt = 0; mt < 4; ++mt)
      #pragma unroll
      for (int r = 0; r < 4; ++r){
        int n = mt*16 + q*4 + r;
        s2[n*64 + (u2 ^ ((n & 4) << 2))] = acc2[mt][r];
      }
  }
  __syncthreads();   // B5: scr2 ready
  if (e2 == 0){
    const float* p0 = (const float*)(ldsb + PTHB);
    const float* p1 = (const float*)(ldsb + PTHB + 16384);
    const float* p2 = (const float*)(ldsb + PTLB);
    float cv = c2[u2];
    const int uc = 64 + u2;
    #pragma unroll
    for (int mt = 0; mt < 4; ++mt)
      #pragma unroll
      for (int r = 0; r < 4; ++r){
        int n = mt*16 + q*4 + r;
        int so = n*64 + (u2 ^ ((n & 4) << 2));
        float h = fast_tanh(acc2[mt][r] + p0[so] + p1[so] + p2[so] + cv);
        f16 hh = (f16)h;
        int unit = ((uc >> 3) ^ (n & 7));
        annh[n*128 + unit*8 + (uc & 7)] = hh;                    // h2 cols 64..127
        annl[n*128 + unit*8 + (uc & 7)] = enc1(h - (float)hh);
      }
  }
  __syncthreads();   // B7: h2 ready; scr2 reads done (PT reusable as pex)

  // ============ aggregation: out = tanh(sum_n sigmoid(.)·tanh(.)) ============
  // each wave: 16 ua columns x 2 mt row-blocks; cross-wave partial via pex.
  const int ua  = (w & 7)*16 + l15;
  const int mth = w >> 3;                         // 0 or 1 -> mt = 2*mth+j
  // uniform selects (no runtime array indexing -> no scratch, rule #20)
  f16x8 n0h = mth ? anh[2] : anh[0], n0l = mth ? anl[2] : anl[0];
  f16x8 n1h = mth ? anh[3] : anh[1], n1l = mth ? anl[3] : anl[1];
  float bib = bi[ua], bjb = bj[ua];
  f32x4 iacc[2], jacc[2];
  iacc[0] = z4; iacc[1] = z4; jacc[0] = z4; jacc[1] = z4;
  #pragma unroll
  for (int ks = 0; ks < 3; ++ks){
    f16x8 wih = *(const f16x8*)&wb[WIT_HI + ua*96 + ks*32 + q*8];
    f16x8 wil = *(const f16x8*)&wb[WIT_LO + ua*96 + ks*32 + q*8];
    f16x8 wjh = *(const f16x8*)&wb[WJT_HI + ua*96 + ks*32 + q*8];
    f16x8 wjl = *(const f16x8*)&wb[WJT_LO + ua*96 + ks*32 + q*8];
    if (ks < 2){
      #pragma unroll
      for (int j = 0; j < 2; ++j){
        int mt = mth*2 + j;
        int off = (mt*16 + l15)*128 + (((8 + ks*4 + q) ^ (l15 & 7)) * 8);
        f16x8 gh = *(const f16x8*)&annh[off];
        f16x8 gl = dec8(&annl[off]);
        iacc[j] = mfma16(gh, wih, iacc[j]);
        iacc[j] = mfma16(gl, wih, iacc[j]);
        iacc[j] = mfma16(gh, wil, iacc[j]);
        jacc[j] = mfma16(gh, wjh, jacc[j]);
        jacc[j] = mfma16(gl, wjh, jacc[j]);
        jacc[j] = mfma16(gh, wjl, jacc[j]);
      }
    } else {
      iacc[0] = mfma16(n0h, wih, iacc[0]);
      iacc[0] = mfma16(n0l, wih, iacc[0]);
      iacc[0] = mfma16(n0h, wil, iacc[0]);
      jacc[0] = mfma16(n0h, wjh, jacc[0]);
      jacc[0] = mfma16(n0l, wjh, jacc[0]);
      jacc[0] = mfma16(n0h, wjl, jacc[0]);
      iacc[1] = mfma16(n1h, wih, iacc[1]);
      iacc[1] = mfma16(n1l, wih, iacc[1]);
      iacc[1] = mfma16(n1h, wil, iacc[1]);
      jacc[1] = mfma16(n1h, wjh, jacc[1]);
      jacc[1] = mfma16(n1l, wjh, jacc[1]);
      jacc[1] = mfma16(n1h, wjl, jacc[1]);
    }
  }
  float s = 0.f;
  #pragma unroll
  for (int j = 0; j < 2; ++j)
    #pragma unroll
    for (int r = 0; r < 4; ++r)
      s += fast_sigmoid(iacc[j][r] + bib) * fast_tanh(jacc[j][r] + bjb);
  s += __shfl_xor(s, 16);
  s += __shfl_xor(s, 32);
  float* pex = (float*)(ldsb + PTHB);             // [2][128] f32
  if (q == 0) pex[mth*128 + ua] = s;
  __syncthreads();   // B8: partials ready
  if (mth == 0 && q == 0)
    out[(size_t)b*128 + ua] = fast_tanh(s + pex[128 + ua]);
}

extern "C" void kernel_launch(void* const* d_in, const int* in_sizes, int n_in,
                              void* d_out, int out_size, void* d_ws, size_t ws_size,
                              hipStream_t stream) {
  (void)in_sizes; (void)n_in; (void)out_size; (void)ws_size;
  const float* adj  = (const float*)d_in[0];
  // d_in[1] = hidden (zeros, rank-2): unused by the reference path
  const float* node = (const float*)d_in[2];
  const float* W1   = (const float*)d_in[3];
  const float* b1   = (const float*)d_in[4];
  const float* V1   = (const float*)d_in[5];
  const float* c1   = (const float*)d_in[6];
  const float* W2   = (const float*)d_in[7];
  const float* b2   = (const float*)d_in[8];
  const float* V2   = (const float*)d_in[9];
  const float* c2   = (const float*)d_in[10];
  const float* Wi   = (const float*)d_in[11];
  const float* bi   = (const float*)d_in[12];
  const float* Wj   = (const float*)d_in[13];
  const float* bj   = (const float*)d_in[14];
  f16* wb    = (f16*)d_ws;
  float* out = (float*)d_out;

  hipFuncSetAttribute((const void*)encoder_main,
                      hipFuncAttributeMaxDynamicSharedMemorySize, LDS_BYTES);

  prep_weights<<<(WS_SRC + 255) / 256, 256, 0, stream>>>(W1, V1, W2, V2, Wi, Wj, wb);
  encoder_main<<<2048, 1024, LDS_BYTES, stream>>>(adj, node, b1, c1, b2, c2, bi, bj, wb, out);
}